// Round 1
// baseline (652.582 us; speedup 1.0000x reference)
//
#include <hip/hip_runtime.h>

#define N_SRC 50000
#define N_DST 50000
#define N_EDGES 1600000
#define D_NEIGH 128
#define D_SELF 128
#define D_EDGE 32
#define D_OUT 256
#define K_TOT 288   // D_SELF + D_NEIGH + D_EDGE split as [0,128)=self, [128,288)=hn
#define D_HN 160

// ---------------- CSR construction ----------------

__global__ void k_deg(const int* __restrict__ dst, int* __restrict__ deg, int n) {
    int i = blockIdx.x * blockDim.x + threadIdx.x;
    if (i < n) atomicAdd(&deg[dst[i]], 1);
}

__global__ __launch_bounds__(1024) void k_scan(const int* __restrict__ deg,
                                               int* __restrict__ row_start,
                                               int* __restrict__ cursor) {
    __shared__ int part[1024];
    const int t = threadIdx.x;
    const int CH = (N_DST + 1023) / 1024;  // 49
    const int b = t * CH;
    int s = 0;
    for (int i = 0; i < CH; i++) {
        int idx = b + i;
        if (idx < N_DST) s += deg[idx];
    }
    part[t] = s;
    __syncthreads();
    // Hillis-Steele inclusive scan over 1024 partials
    for (int off = 1; off < 1024; off <<= 1) {
        int v = (t >= off) ? part[t - off] : 0;
        __syncthreads();
        part[t] += v;
        __syncthreads();
    }
    int ex = (t == 0) ? 0 : part[t - 1];
    for (int i = 0; i < CH; i++) {
        int idx = b + i;
        if (idx < N_DST) {
            row_start[idx] = ex;
            cursor[idx] = ex;
            ex += deg[idx];
        }
    }
    if (t == 1023) row_start[N_DST] = part[1023];
}

__global__ void k_fill(const int* __restrict__ dst, int* __restrict__ cursor,
                       int* __restrict__ eids, int n) {
    int i = blockIdx.x * blockDim.x + threadIdx.x;
    if (i < n) {
        int p = atomicAdd(&cursor[dst[i]], 1);
        eids[p] = i;
    }
}

// ---------------- Aggregation: one wave per dst node ----------------
// lane handles h_neigh dims {lane, lane+64}; lanes 0..31 also handle edge dims.

__global__ __launch_bounds__(64) void k_agg(const int* __restrict__ row_start,
                                            const int* __restrict__ eids,
                                            const int* __restrict__ src,
                                            const float* __restrict__ h_neigh,
                                            const float* __restrict__ ef,
                                            float* __restrict__ hn) {
    const int d = blockIdx.x;
    const int lane = threadIdx.x;
    const int start = row_start[d];
    const int end = row_start[d + 1];
    const int deg = end - start;
    float a0 = 0.f, a1 = 0.f, a2 = 0.f;
    for (int i = 0; i < deg; i++) {
        int e = __builtin_amdgcn_readfirstlane(eids[start + i]);
        int s = __builtin_amdgcn_readfirstlane(src[e]);
        const float* hp = h_neigh + (size_t)s * D_NEIGH;
        a0 += hp[lane];
        a1 += hp[lane + 64];
        if (lane < D_EDGE) a2 += ef[(size_t)e * D_EDGE + lane];
    }
    const float inv = 1.0f / (float)(deg > 0 ? deg : 1);
    float* o = hn + (size_t)d * D_HN;
    o[lane] = a0 * inv;
    o[lane + 64] = a1 * inv;
    if (lane < D_EDGE) o[128 + lane] = a2 * inv;
}

// ---------------- GEMM: z = relu(X @ W^T), X = [h_self | hn], W = [W_self | W_neigh]
// BM=64, BN=64, BK=32, 256 threads, 4x4 micro-tile per thread.

#define BM 64
#define BN 64
#define BK 32

__global__ __launch_bounds__(256) void k_gemm(const float* __restrict__ h_self,
                                              const float* __restrict__ hn,
                                              const float* __restrict__ Wself,
                                              const float* __restrict__ Wneigh,
                                              float* __restrict__ out) {
    __shared__ float Xs[BK][BM + 4];
    __shared__ float Ws[BK][BN + 4];
    const int tid = threadIdx.x;
    const int tx = tid & 15;        // 0..15 -> 4 cols each
    const int ty = tid >> 4;        // 0..15 -> 4 rows each
    const int brow = blockIdx.x * BM;
    const int bcol = blockIdx.y * BN;

    float acc[4][4] = {};

    const int lm = tid >> 2;          // 0..63 (tile row / tile col)
    const int kq = (tid & 3) * 8;     // 0,8,16,24

    for (int k0 = 0; k0 < K_TOT; k0 += BK) {
        // ---- load X tile (64 rows x 32 k) ----
        {
            float xv[8];
            const int gm = brow + lm;
            const int k = k0 + kq;
            if (gm < N_DST) {
                const float* sp;
                int kk;
                if (k < 128) { sp = h_self + (size_t)gm * D_SELF; kk = k; }
                else         { sp = hn + (size_t)gm * D_HN;       kk = k - 128; }
                float4 v0 = *(const float4*)(sp + kk);
                float4 v1 = *(const float4*)(sp + kk + 4);
                xv[0] = v0.x; xv[1] = v0.y; xv[2] = v0.z; xv[3] = v0.w;
                xv[4] = v1.x; xv[5] = v1.y; xv[6] = v1.z; xv[7] = v1.w;
            } else {
#pragma unroll
                for (int j = 0; j < 8; j++) xv[j] = 0.f;
            }
#pragma unroll
            for (int j = 0; j < 8; j++) Xs[kq + j][lm] = xv[j];
        }
        // ---- load W tile (64 cols x 32 k) ----
        {
            const int gj = bcol + lm;  // output col, always < 256
            const int k = k0 + kq;
            const float* wp;
            int kk;
            if (k < 128) { wp = Wself + (size_t)gj * D_SELF;  kk = k; }
            else         { wp = Wneigh + (size_t)gj * D_HN;   kk = k - 128; }
            float4 w0 = *(const float4*)(wp + kk);
            float4 w1 = *(const float4*)(wp + kk + 4);
            Ws[kq + 0][lm] = w0.x; Ws[kq + 1][lm] = w0.y;
            Ws[kq + 2][lm] = w0.z; Ws[kq + 3][lm] = w0.w;
            Ws[kq + 4][lm] = w1.x; Ws[kq + 5][lm] = w1.y;
            Ws[kq + 6][lm] = w1.z; Ws[kq + 7][lm] = w1.w;
        }
        __syncthreads();
#pragma unroll
        for (int k = 0; k < BK; k++) {
            float4 x = *(const float4*)&Xs[k][ty * 4];
            float4 w = *(const float4*)&Ws[k][tx * 4];
            float xr[4] = {x.x, x.y, x.z, x.w};
            float wc[4] = {w.x, w.y, w.z, w.w};
#pragma unroll
            for (int r = 0; r < 4; r++)
#pragma unroll
                for (int c = 0; c < 4; c++)
                    acc[r][c] = fmaf(xr[r], wc[c], acc[r][c]);
        }
        __syncthreads();
    }

#pragma unroll
    for (int r = 0; r < 4; r++) {
        const int row = brow + ty * 4 + r;
        if (row < N_DST) {
#pragma unroll
            for (int c = 0; c < 4; c++) {
                const int col = bcol + tx * 4 + c;
                out[(size_t)row * D_OUT + col] = fmaxf(acc[r][c], 0.f);
            }
        }
    }
}

// ---------------- Row L2 normalization (in place) ----------------

__global__ __launch_bounds__(256) void k_norm(float* __restrict__ out) {
    const int row = blockIdx.x * 4 + (threadIdx.x >> 6);
    const int lane = threadIdx.x & 63;
    if (row >= N_DST) return;
    float4 v = *(float4*)&out[(size_t)row * D_OUT + lane * 4];
    float ss = v.x * v.x + v.y * v.y + v.z * v.z + v.w * v.w;
#pragma unroll
    for (int off = 32; off; off >>= 1) ss += __shfl_xor(ss, off);
    float n = sqrtf(ss);
    float inv = (n == 0.f) ? 1.f : 1.f / n;
    v.x *= inv; v.y *= inv; v.z *= inv; v.w *= inv;
    *(float4*)&out[(size_t)row * D_OUT + lane * 4] = v;
}

// ---------------- launch ----------------

extern "C" void kernel_launch(void* const* d_in, const int* in_sizes, int n_in,
                              void* d_out, int out_size, void* d_ws, size_t ws_size,
                              hipStream_t stream) {
    const float* h_neigh = (const float*)d_in[0];
    const float* h_self  = (const float*)d_in[1];
    const float* ef      = (const float*)d_in[2];
    const int*   src     = (const int*)d_in[3];
    const int*   dst     = (const int*)d_in[4];
    const float* Wself   = (const float*)d_in[5];
    const float* Wneigh  = (const float*)d_in[6];
    float* out = (float*)d_out;

    char* ws = (char*)d_ws;
    int* deg       = (int*)(ws + 0);          // 50000 ints
    int* row_start = (int*)(ws + 262144);     // 50001 ints
    int* cursor    = (int*)(ws + 524288);     // 50000 ints
    int* eids      = (int*)(ws + 786432);     // 1.6M ints (6.4 MB)
    float* hn      = (float*)(ws + 8388608);  // 50000*160 f32 (32 MB) -> ends ~40.4 MB

    hipMemsetAsync(deg, 0, N_DST * sizeof(int), stream);
    k_deg<<<(N_EDGES + 255) / 256, 256, 0, stream>>>(dst, deg, N_EDGES);
    k_scan<<<1, 1024, 0, stream>>>(deg, row_start, cursor);
    k_fill<<<(N_EDGES + 255) / 256, 256, 0, stream>>>(dst, cursor, eids, N_EDGES);
    k_agg<<<N_DST, 64, 0, stream>>>(row_start, eids, src, h_neigh, ef, hn);

    dim3 g((N_DST + BM - 1) / BM, D_OUT / BN);
    k_gemm<<<g, 256, 0, stream>>>(h_self, hn, Wself, Wneigh, out);

    k_norm<<<(N_DST + 3) / 4, 256, 0, stream>>>(out);
}

// Round 2
// 624.954 us; speedup vs baseline: 1.0442x; 1.0442x over previous
//
#include <hip/hip_runtime.h>

#define N_SRC 50000
#define N_DST 50000
#define N_EDGES 1600000
#define D_NEIGH 128
#define D_SELF 128
#define D_EDGE 32
#define D_OUT 256
#define K_TOT 288   // D_SELF + D_NEIGH + D_EDGE split as [0,128)=self, [128,288)=hn
#define D_HN 160

// ---------------- CSR construction ----------------

__global__ void k_deg(const int* __restrict__ dst, int* __restrict__ deg, int n) {
    int i = blockIdx.x * blockDim.x + threadIdx.x;
    if (i < n) atomicAdd(&deg[dst[i]], 1);
}

__global__ __launch_bounds__(1024) void k_scan(const int* __restrict__ deg,
                                               int* __restrict__ row_start,
                                               int* __restrict__ cursor) {
    __shared__ int part[1024];
    const int t = threadIdx.x;
    const int CH = (N_DST + 1023) / 1024;  // 49
    const int b = t * CH;
    int s = 0;
    for (int i = 0; i < CH; i++) {
        int idx = b + i;
        if (idx < N_DST) s += deg[idx];
    }
    part[t] = s;
    __syncthreads();
    // Hillis-Steele inclusive scan over 1024 partials
    for (int off = 1; off < 1024; off <<= 1) {
        int v = (t >= off) ? part[t - off] : 0;
        __syncthreads();
        part[t] += v;
        __syncthreads();
    }
    int ex = (t == 0) ? 0 : part[t - 1];
    for (int i = 0; i < CH; i++) {
        int idx = b + i;
        if (idx < N_DST) {
            row_start[idx] = ex;
            cursor[idx] = ex;
            ex += deg[idx];
        }
    }
    if (t == 1023) row_start[N_DST] = part[1023];
}

__global__ void k_fill(const int* __restrict__ dst, int* __restrict__ cursor,
                       int* __restrict__ eids, int n) {
    int i = blockIdx.x * blockDim.x + threadIdx.x;
    if (i < n) {
        int p = atomicAdd(&cursor[dst[i]], 1);
        eids[p] = i;
    }
}

// ---------------- Aggregation: one wave per dst node ----------------
// Chunked: load up to 64 edge ids + src ids in parallel across lanes (breaks
// the per-edge dependent chain), then readlane-broadcast inside an unrolled
// loop so 8+ gathers are in flight per wave.
// Lane i accumulates h_neigh dims {2i, 2i+1} as float2; lanes 0..31 also
// accumulate the 32 edge-feature dims.

__global__ __launch_bounds__(64) void k_agg(const int* __restrict__ row_start,
                                            const int* __restrict__ eids,
                                            const int* __restrict__ src,
                                            const float* __restrict__ h_neigh,
                                            const float* __restrict__ ef,
                                            float* __restrict__ hn) {
    const int d = blockIdx.x;
    const int lane = threadIdx.x;
    const int start = row_start[d];
    const int end = row_start[d + 1];
    const int deg = end - start;
    float ax = 0.f, ay = 0.f, ae = 0.f;

    for (int c = start; c < end; c += 64) {
        const int rem = end - c;
        const int m = rem < 64 ? rem : 64;
        int e = 0, s = 0;
        if (lane < m) {
            e = eids[c + lane];   // coalesced
            s = src[e];           // 64 parallel 4B gathers
        }
#pragma unroll 8
        for (int i = 0; i < m; ++i) {
            const int si = __builtin_amdgcn_readlane(s, i);
            const int ei = __builtin_amdgcn_readlane(e, i);
            const float2 v = *(const float2*)(h_neigh + (size_t)si * D_NEIGH + 2 * lane);
            ax += v.x;
            ay += v.y;
            if (lane < D_EDGE) ae += ef[(size_t)ei * D_EDGE + lane];
        }
    }

    const float inv = 1.0f / (float)(deg > 0 ? deg : 1);
    float* o = hn + (size_t)d * D_HN;
    *(float2*)(o + 2 * lane) = make_float2(ax * inv, ay * inv);
    if (lane < D_EDGE) o[128 + lane] = ae * inv;
}

// ---------------- GEMM: z = relu(X @ W^T), X = [h_self | hn], W = [W_self | W_neigh]
// BM=64, BN=64, BK=32, 256 threads, 4x4 micro-tile per thread.

#define BM 64
#define BN 64
#define BK 32

__global__ __launch_bounds__(256) void k_gemm(const float* __restrict__ h_self,
                                              const float* __restrict__ hn,
                                              const float* __restrict__ Wself,
                                              const float* __restrict__ Wneigh,
                                              float* __restrict__ out) {
    __shared__ float Xs[BK][BM + 4];
    __shared__ float Ws[BK][BN + 4];
    const int tid = threadIdx.x;
    const int tx = tid & 15;        // 0..15 -> 4 cols each
    const int ty = tid >> 4;        // 0..15 -> 4 rows each
    const int brow = blockIdx.x * BM;
    const int bcol = blockIdx.y * BN;

    float acc[4][4] = {};

    const int lm = tid >> 2;          // 0..63 (tile row / tile col)
    const int kq = (tid & 3) * 8;     // 0,8,16,24

    for (int k0 = 0; k0 < K_TOT; k0 += BK) {
        // ---- load X tile (64 rows x 32 k) ----
        {
            float xv[8];
            const int gm = brow + lm;
            const int k = k0 + kq;
            if (gm < N_DST) {
                const float* sp;
                int kk;
                if (k < 128) { sp = h_self + (size_t)gm * D_SELF; kk = k; }
                else         { sp = hn + (size_t)gm * D_HN;       kk = k - 128; }
                float4 v0 = *(const float4*)(sp + kk);
                float4 v1 = *(const float4*)(sp + kk + 4);
                xv[0] = v0.x; xv[1] = v0.y; xv[2] = v0.z; xv[3] = v0.w;
                xv[4] = v1.x; xv[5] = v1.y; xv[6] = v1.z; xv[7] = v1.w;
            } else {
#pragma unroll
                for (int j = 0; j < 8; j++) xv[j] = 0.f;
            }
#pragma unroll
            for (int j = 0; j < 8; j++) Xs[kq + j][lm] = xv[j];
        }
        // ---- load W tile (64 cols x 32 k) ----
        {
            const int gj = bcol + lm;  // output col, always < 256
            const int k = k0 + kq;
            const float* wp;
            int kk;
            if (k < 128) { wp = Wself + (size_t)gj * D_SELF;  kk = k; }
            else         { wp = Wneigh + (size_t)gj * D_HN;   kk = k - 128; }
            float4 w0 = *(const float4*)(wp + kk);
            float4 w1 = *(const float4*)(wp + kk + 4);
            Ws[kq + 0][lm] = w0.x; Ws[kq + 1][lm] = w0.y;
            Ws[kq + 2][lm] = w0.z; Ws[kq + 3][lm] = w0.w;
            Ws[kq + 4][lm] = w1.x; Ws[kq + 5][lm] = w1.y;
            Ws[kq + 6][lm] = w1.z; Ws[kq + 7][lm] = w1.w;
        }
        __syncthreads();
#pragma unroll
        for (int k = 0; k < BK; k++) {
            float4 x = *(const float4*)&Xs[k][ty * 4];
            float4 w = *(const float4*)&Ws[k][tx * 4];
            float xr[4] = {x.x, x.y, x.z, x.w};
            float wc[4] = {w.x, w.y, w.z, w.w};
#pragma unroll
            for (int r = 0; r < 4; r++)
#pragma unroll
                for (int c = 0; c < 4; c++)
                    acc[r][c] = fmaf(xr[r], wc[c], acc[r][c]);
        }
        __syncthreads();
    }

#pragma unroll
    for (int r = 0; r < 4; r++) {
        const int row = brow + ty * 4 + r;
        if (row < N_DST) {
#pragma unroll
            for (int c = 0; c < 4; c++) {
                const int col = bcol + tx * 4 + c;
                out[(size_t)row * D_OUT + col] = fmaxf(acc[r][c], 0.f);
            }
        }
    }
}

// ---------------- Row L2 normalization (in place) ----------------

__global__ __launch_bounds__(256) void k_norm(float* __restrict__ out) {
    const int row = blockIdx.x * 4 + (threadIdx.x >> 6);
    const int lane = threadIdx.x & 63;
    if (row >= N_DST) return;
    float4 v = *(float4*)&out[(size_t)row * D_OUT + lane * 4];
    float ss = v.x * v.x + v.y * v.y + v.z * v.z + v.w * v.w;
#pragma unroll
    for (int off = 32; off; off >>= 1) ss += __shfl_xor(ss, off);
    float n = sqrtf(ss);
    float inv = (n == 0.f) ? 1.f : 1.f / n;
    v.x *= inv; v.y *= inv; v.z *= inv; v.w *= inv;
    *(float4*)&out[(size_t)row * D_OUT + lane * 4] = v;
}

// ---------------- launch ----------------

extern "C" void kernel_launch(void* const* d_in, const int* in_sizes, int n_in,
                              void* d_out, int out_size, void* d_ws, size_t ws_size,
                              hipStream_t stream) {
    const float* h_neigh = (const float*)d_in[0];
    const float* h_self  = (const float*)d_in[1];
    const float* ef      = (const float*)d_in[2];
    const int*   src     = (const int*)d_in[3];
    const int*   dst     = (const int*)d_in[4];
    const float* Wself   = (const float*)d_in[5];
    const float* Wneigh  = (const float*)d_in[6];
    float* out = (float*)d_out;

    char* ws = (char*)d_ws;
    int* deg       = (int*)(ws + 0);          // 50000 ints
    int* row_start = (int*)(ws + 262144);     // 50001 ints
    int* cursor    = (int*)(ws + 524288);     // 50000 ints
    int* eids      = (int*)(ws + 786432);     // 1.6M ints (6.4 MB)
    float* hn      = (float*)(ws + 8388608);  // 50000*160 f32 (32 MB) -> ends ~40.4 MB

    hipMemsetAsync(deg, 0, N_DST * sizeof(int), stream);
    k_deg<<<(N_EDGES + 255) / 256, 256, 0, stream>>>(dst, deg, N_EDGES);
    k_scan<<<1, 1024, 0, stream>>>(deg, row_start, cursor);
    k_fill<<<(N_EDGES + 255) / 256, 256, 0, stream>>>(dst, cursor, eids, N_EDGES);
    k_agg<<<N_DST, 64, 0, stream>>>(row_start, eids, src, h_neigh, ef, hn);

    dim3 g((N_DST + BM - 1) / BM, D_OUT / BN);
    k_gemm<<<g, 256, 0, stream>>>(h_self, hn, Wself, Wneigh, out);

    k_norm<<<(N_DST + 3) / 4, 256, 0, stream>>>(out);
}

// Round 3
// 550.667 us; speedup vs baseline: 1.1851x; 1.1349x over previous
//
#include <hip/hip_runtime.h>

#define N_SRC 50000
#define N_DST 50000
#define N_EDGES 1600000
#define D_NEIGH 128
#define D_SELF 128
#define D_EDGE 32
#define D_OUT 256
#define K_TOT 288   // D_SELF + D_NEIGH + D_EDGE split as [0,128)=self, [128,288)=hn
#define D_HN 160

// ---------------- CSR construction ----------------

__global__ void k_deg(const int* __restrict__ dst, int* __restrict__ deg, int n) {
    int i = blockIdx.x * blockDim.x + threadIdx.x;
    if (i < n) atomicAdd(&deg[dst[i]], 1);
}

__global__ __launch_bounds__(1024) void k_scan(const int* __restrict__ deg,
                                               int* __restrict__ row_start,
                                               int* __restrict__ cursor) {
    __shared__ int part[1024];
    const int t = threadIdx.x;
    const int CH = (N_DST + 1023) / 1024;  // 49
    const int b = t * CH;
    int s = 0;
    for (int i = 0; i < CH; i++) {
        int idx = b + i;
        if (idx < N_DST) s += deg[idx];
    }
    part[t] = s;
    __syncthreads();
    for (int off = 1; off < 1024; off <<= 1) {
        int v = (t >= off) ? part[t - off] : 0;
        __syncthreads();
        part[t] += v;
        __syncthreads();
    }
    int ex = (t == 0) ? 0 : part[t - 1];
    for (int i = 0; i < CH; i++) {
        int idx = b + i;
        if (idx < N_DST) {
            row_start[idx] = ex;
            cursor[idx] = ex;
            ex += deg[idx];
        }
    }
    if (t == 1023) row_start[N_DST] = part[1023];
}

// fill CSR edge list; optionally also CSR-ordered src ids (breaks the
// eids->src dependent-gather chain in k_agg).
template <bool HAS_SSRC>
__global__ void k_fill(const int* __restrict__ dst, const int* __restrict__ src,
                       int* __restrict__ cursor,
                       int* __restrict__ eids, int* __restrict__ ssrc, int n) {
    int i = blockIdx.x * blockDim.x + threadIdx.x;
    if (i < n) {
        int p = atomicAdd(&cursor[dst[i]], 1);
        eids[p] = i;
        if (HAS_SSRC) ssrc[p] = src[i];
    }
}

// ---------------- Aggregation: one wave per dst node ----------------
// 64-edge chunks: edge ids + src ids loaded coalesced across lanes, then
// readlane-broadcast. Explicit load-then-accumulate arrays force ~12 gathers
// in flight per 8-edge group (R2 had VGPR=12 -> serialized loads).
// Lane i owns h_neigh dims {2i,2i+1}; for edge features lanes 0-31 take even
// edges, 32-63 odd edges (combined with one shfl_xor at the end).

template <bool HAS_SSRC>
__global__ __launch_bounds__(64) void k_agg(const int* __restrict__ row_start,
                                            const int* __restrict__ eids,
                                            const int* __restrict__ ssrc,
                                            const int* __restrict__ src,
                                            const float* __restrict__ h_neigh,
                                            const float* __restrict__ ef,
                                            float* __restrict__ hn) {
    const int d = blockIdx.x;
    const int lane = threadIdx.x;
    const int start = row_start[d];
    const int end = row_start[d + 1];
    const int deg = end - start;
    float ax = 0.f, ay = 0.f, ae = 0.f;
    const float* hbase = h_neigh + 2 * lane;
    const float* ebase = ef + (lane & 31);
    const int g = lane >> 5;

    for (int c = start; c < end; c += 64) {
        const int rem = end - c;
        const int m = rem < 64 ? rem : 64;
        int e = 0, s = 0;
        if (lane < m) {
            e = eids[c + lane];                       // coalesced
            s = HAS_SSRC ? ssrc[c + lane] : src[e];   // coalesced (or gather fallback)
        }
        int i = 0;
        for (; i + 8 <= m; i += 8) {
            float2 t[8];
            float te[4];
#pragma unroll
            for (int j = 0; j < 8; j++) {
                const int si = __builtin_amdgcn_readlane(s, i + j);
                t[j] = *(const float2*)(hbase + (size_t)si * D_NEIGH);
            }
#pragma unroll
            for (int j = 0; j < 4; j++) {
                const int ee = __shfl(e, i + 2 * j + g);   // lanes 0-31: even edge, 32-63: odd
                te[j] = ebase[(size_t)ee * D_EDGE];
            }
#pragma unroll
            for (int j = 0; j < 8; j++) { ax += t[j].x; ay += t[j].y; }
#pragma unroll
            for (int j = 0; j < 4; j++) ae += te[j];
        }
        for (; i < m; ++i) {
            const int si = __builtin_amdgcn_readlane(s, i);
            const int ei = __builtin_amdgcn_readlane(e, i);
            const float2 v = *(const float2*)(hbase + (size_t)si * D_NEIGH);
            ax += v.x; ay += v.y;
            if (lane < D_EDGE) ae += ef[(size_t)ei * D_EDGE + lane];
        }
    }

    ae += __shfl_xor(ae, 32);  // combine even-lane / odd-lane edge-feature partials

    const float inv = 1.0f / (float)(deg > 0 ? deg : 1);
    float* o = hn + (size_t)d * D_HN;
    *(float2*)(o + 2 * lane) = make_float2(ax * inv, ay * inv);
    if (lane < D_EDGE) o[128 + lane] = ae * inv;
}

// ---------------- GEMM: z = relu(X @ W^T), X = [h_self | hn], W = [W_self | W_neigh]

#define BM 64
#define BN 64
#define BK 32

__global__ __launch_bounds__(256) void k_gemm(const float* __restrict__ h_self,
                                              const float* __restrict__ hn,
                                              const float* __restrict__ Wself,
                                              const float* __restrict__ Wneigh,
                                              float* __restrict__ out) {
    __shared__ float Xs[BK][BM + 4];
    __shared__ float Ws[BK][BN + 4];
    const int tid = threadIdx.x;
    const int tx = tid & 15;
    const int ty = tid >> 4;
    const int brow = blockIdx.x * BM;
    const int bcol = blockIdx.y * BN;

    float acc[4][4] = {};

    const int lm = tid >> 2;
    const int kq = (tid & 3) * 8;

    for (int k0 = 0; k0 < K_TOT; k0 += BK) {
        {
            float xv[8];
            const int gm = brow + lm;
            const int k = k0 + kq;
            if (gm < N_DST) {
                const float* sp;
                int kk;
                if (k < 128) { sp = h_self + (size_t)gm * D_SELF; kk = k; }
                else         { sp = hn + (size_t)gm * D_HN;       kk = k - 128; }
                float4 v0 = *(const float4*)(sp + kk);
                float4 v1 = *(const float4*)(sp + kk + 4);
                xv[0] = v0.x; xv[1] = v0.y; xv[2] = v0.z; xv[3] = v0.w;
                xv[4] = v1.x; xv[5] = v1.y; xv[6] = v1.z; xv[7] = v1.w;
            } else {
#pragma unroll
                for (int j = 0; j < 8; j++) xv[j] = 0.f;
            }
#pragma unroll
            for (int j = 0; j < 8; j++) Xs[kq + j][lm] = xv[j];
        }
        {
            const int gj = bcol + lm;
            const int k = k0 + kq;
            const float* wp;
            int kk;
            if (k < 128) { wp = Wself + (size_t)gj * D_SELF;  kk = k; }
            else         { wp = Wneigh + (size_t)gj * D_HN;   kk = k - 128; }
            float4 w0 = *(const float4*)(wp + kk);
            float4 w1 = *(const float4*)(wp + kk + 4);
            Ws[kq + 0][lm] = w0.x; Ws[kq + 1][lm] = w0.y;
            Ws[kq + 2][lm] = w0.z; Ws[kq + 3][lm] = w0.w;
            Ws[kq + 4][lm] = w1.x; Ws[kq + 5][lm] = w1.y;
            Ws[kq + 6][lm] = w1.z; Ws[kq + 7][lm] = w1.w;
        }
        __syncthreads();
#pragma unroll
        for (int k = 0; k < BK; k++) {
            float4 x = *(const float4*)&Xs[k][ty * 4];
            float4 w = *(const float4*)&Ws[k][tx * 4];
            float xr[4] = {x.x, x.y, x.z, x.w};
            float wc[4] = {w.x, w.y, w.z, w.w};
#pragma unroll
            for (int r = 0; r < 4; r++)
#pragma unroll
                for (int c = 0; c < 4; c++)
                    acc[r][c] = fmaf(xr[r], wc[c], acc[r][c]);
        }
        __syncthreads();
    }

#pragma unroll
    for (int r = 0; r < 4; r++) {
        const int row = brow + ty * 4 + r;
        if (row < N_DST) {
#pragma unroll
            for (int c = 0; c < 4; c++) {
                const int col = bcol + tx * 4 + c;
                out[(size_t)row * D_OUT + col] = fmaxf(acc[r][c], 0.f);
            }
        }
    }
}

// ---------------- Row L2 normalization (in place) ----------------

__global__ __launch_bounds__(256) void k_norm(float* __restrict__ out) {
    const int row = blockIdx.x * 4 + (threadIdx.x >> 6);
    const int lane = threadIdx.x & 63;
    if (row >= N_DST) return;
    float4 v = *(float4*)&out[(size_t)row * D_OUT + lane * 4];
    float ss = v.x * v.x + v.y * v.y + v.z * v.z + v.w * v.w;
#pragma unroll
    for (int off = 32; off; off >>= 1) ss += __shfl_xor(ss, off);
    float n = sqrtf(ss);
    float inv = (n == 0.f) ? 1.f : 1.f / n;
    v.x *= inv; v.y *= inv; v.z *= inv; v.w *= inv;
    *(float4*)&out[(size_t)row * D_OUT + lane * 4] = v;
}

// ---------------- launch ----------------

extern "C" void kernel_launch(void* const* d_in, const int* in_sizes, int n_in,
                              void* d_out, int out_size, void* d_ws, size_t ws_size,
                              hipStream_t stream) {
    const float* h_neigh = (const float*)d_in[0];
    const float* h_self  = (const float*)d_in[1];
    const float* ef      = (const float*)d_in[2];
    const int*   src     = (const int*)d_in[3];
    const int*   dst     = (const int*)d_in[4];
    const float* Wself   = (const float*)d_in[5];
    const float* Wneigh  = (const float*)d_in[6];
    float* out = (float*)d_out;

    char* ws = (char*)d_ws;
    int* deg       = (int*)(ws + 0);          // 50000 ints
    int* row_start = (int*)(ws + 262144);     // 50001 ints
    int* cursor    = (int*)(ws + 524288);     // 50000 ints
    int* eids      = (int*)(ws + 786432);     // 1.6M ints, ends 7186432

    const size_t need_big = 786432 + 2 * 6400000 + 32000000;  // ~45.6 MB
    const bool big = ws_size >= need_big;
    int* ssrc;
    float* hn;
    if (big) {
        ssrc = (int*)(ws + 7186432);          // 1.6M ints, ends 13586432
        hn   = (float*)(ws + 13586432);       // 32 MB, ends ~45.6 MB
    } else {
        ssrc = eids;                          // unused in fallback
        hn   = (float*)(ws + 8388608);        // old layout, ends ~40.4 MB
    }

    hipMemsetAsync(deg, 0, N_DST * sizeof(int), stream);
    k_deg<<<(N_EDGES + 255) / 256, 256, 0, stream>>>(dst, deg, N_EDGES);
    k_scan<<<1, 1024, 0, stream>>>(deg, row_start, cursor);
    if (big) {
        k_fill<true><<<(N_EDGES + 255) / 256, 256, 0, stream>>>(dst, src, cursor, eids, ssrc, N_EDGES);
        k_agg<true><<<N_DST, 64, 0, stream>>>(row_start, eids, ssrc, src, h_neigh, ef, hn);
    } else {
        k_fill<false><<<(N_EDGES + 255) / 256, 256, 0, stream>>>(dst, src, cursor, eids, ssrc, N_EDGES);
        k_agg<false><<<N_DST, 64, 0, stream>>>(row_start, eids, ssrc, src, h_neigh, ef, hn);
    }

    dim3 g((N_DST + BM - 1) / BM, D_OUT / BN);
    k_gemm<<<g, 256, 0, stream>>>(h_self, hn, Wself, Wneigh, out);

    k_norm<<<(N_DST + 3) / 4, 256, 0, stream>>>(out);
}